// Round 7
// baseline (869.232 us; speedup 1.0000x reference)
//
#include <hip/hip_runtime.h>
#include <cstddef>
#include <cstdint>
#include <math.h>

#define NN   8192
#define FF   256
#define RESH 512
#define REPH 256
#define EMBD 128
#define EE   262144
#define GAMMA_ 0.1f

typedef __attribute__((ext_vector_type(8))) short bf16x8;
typedef __attribute__((ext_vector_type(4))) float f32x4;
typedef __attribute__((ext_vector_type(2))) float f32x2;
typedef __attribute__((ext_vector_type(4))) short s16x4;
typedef __attribute__((ext_vector_type(2))) short s16x2;

// split fp32 -> hi/lo bf16 (RTNE both): x ~= hi + lo with rel err ~2^-17
__device__ inline void f2hilo(float x, short& h, short& l) {
  unsigned u = __float_as_uint(x);
  unsigned r = u + 0x7FFFu + ((u >> 16) & 1u);
  h = (short)(r >> 16);
  float hf = __uint_as_float(r & 0xFFFF0000u);
  float lf = x - hf;
  unsigned u2 = __float_as_uint(lf);
  unsigned r2 = u2 + 0x7FFFu + ((u2 >> 16) & 1u);
  l = (short)(r2 >> 16);
}

// ---------------- CSR construction ----------------

__global__ void count_kernel(const int* __restrict__ ei, int* __restrict__ cnt_src,
                             int* __restrict__ cnt_dst) {
  int e = blockIdx.x * blockDim.x + threadIdx.x;
  if (e < EE) {
    atomicAdd(&cnt_src[ei[e]], 1);
    atomicAdd(&cnt_dst[ei[EE + e]], 1);
  }
}

__global__ void scan_kernel(const int* __restrict__ cnt_src, const int* __restrict__ cnt_dst,
                            int* __restrict__ off_src, int* __restrict__ off_dst,
                            float* __restrict__ dinv) {
  const int* cnt = blockIdx.x ? cnt_dst : cnt_src;
  int* off = blockIdx.x ? off_dst : off_src;
  __shared__ int sm[1024];
  int carry = 0;
  for (int ch = 0; ch < NN / 1024; ++ch) {
    int idx = ch * 1024 + threadIdx.x;
    int v = cnt[idx];
    if (blockIdx.x) dinv[idx] = rsqrtf((float)v + 1.0f);
    int x = v;
    sm[threadIdx.x] = x;
    __syncthreads();
    for (int ofs = 1; ofs < 1024; ofs <<= 1) {
      int y = (threadIdx.x >= ofs) ? sm[threadIdx.x - ofs] : 0;
      __syncthreads();
      x += y;
      sm[threadIdx.x] = x;
      __syncthreads();
    }
    off[idx] = x - v + carry;
    carry += sm[1023];
    __syncthreads();
  }
  if (threadIdx.x == 0) off[NN] = carry;
}

__global__ void fill_kernel(const int* __restrict__ ei, const int* __restrict__ off_src,
                            const int* __restrict__ off_dst, int* __restrict__ cur_src,
                            int* __restrict__ cur_dst, int* __restrict__ adj_src,
                            int* __restrict__ adj_dst) {
  int e = blockIdx.x * blockDim.x + threadIdx.x;
  if (e < EE) {
    int s = ei[e], d = ei[EE + e];
    int ps = atomicAdd(&cur_src[s], 1);
    adj_src[off_src[s] + ps] = d;
    int pd = atomicAdd(&cur_dst[d], 1);
    adj_dst[off_dst[d] + pd] = s;
  }
}

// ---------------- phased sparse A @ res_W1 (table slice 2048 rows = 4 MB, L2-fits) ----
__global__ __launch_bounds__(256) void s1_ph(const float* __restrict__ W1,
    const float* __restrict__ b1, const int* __restrict__ off_src,
    const int* __restrict__ adj_src, float* __restrict__ S1f,
    short* __restrict__ S1h, short* __restrict__ S1l, int lo, int first, int last) {
  __shared__ f32x4 p2[2][64];
  const int i = blockIdx.x, w = threadIdx.x >> 6, lane = threadIdx.x & 63;
  const int half = w & 1, par = w >> 1;
  const int col = half * 256 + lane * 4;
  const float* base = W1 + col;
  const int beg = off_src[i], end = off_src[i + 1];
  f32x4 acc = {};
  int k = beg + par;
  for (; k + 6 < end; k += 8) {
    int s0 = adj_src[k], s1 = adj_src[k + 2], s2 = adj_src[k + 4], s3 = adj_src[k + 6];
    if ((unsigned)(s0 - lo) < 2048u) acc += *(const f32x4*)(base + (size_t)s0 * RESH);
    if ((unsigned)(s1 - lo) < 2048u) acc += *(const f32x4*)(base + (size_t)s1 * RESH);
    if ((unsigned)(s2 - lo) < 2048u) acc += *(const f32x4*)(base + (size_t)s2 * RESH);
    if ((unsigned)(s3 - lo) < 2048u) acc += *(const f32x4*)(base + (size_t)s3 * RESH);
  }
  for (; k < end; k += 2) {
    int s = adj_src[k];
    if ((unsigned)(s - lo) < 2048u) acc += *(const f32x4*)(base + (size_t)s * RESH);
  }
  if (par == 1) p2[half][lane] = acc;
  __syncthreads();
  if (par == 0) {
    acc += p2[half][lane];
    size_t o = (size_t)i * RESH + col;
    if (!first) acc += *(const f32x4*)(S1f + o);
    if (!last) {
      *(f32x4*)(S1f + o) = acc;
    } else {
      f32x4 bb = *(const f32x4*)(b1 + col);
      s16x4 vh, vl;
#pragma unroll
      for (int j = 0; j < 4; ++j) {
        float v = fmaxf(acc[j] + bb[j], 0.f);
        short hh, ll;
        f2hilo(v, hh, ll);
        vh[j] = hh; vl[j] = ll;
      }
      *(s16x4*)(S1h + o) = vh;
      *(s16x4*)(S1l + o) = vl;
    }
  }
}

// ---------------- phased agg layer0 (no norm); table slice 4096 rows = 4 MB ----------
__global__ __launch_bounds__(256) void agg0_ph(const float* __restrict__ h,
    const float* __restrict__ b, const float* __restrict__ mod,
    const int* __restrict__ off_dst, const int* __restrict__ adj_dst,
    float* __restrict__ Pf, short* __restrict__ oh, short* __restrict__ ol,
    int lo, int first, int last) {
  __shared__ f32x4 part[3][64];
  const int d = blockIdx.x, w = threadIdx.x >> 6, lane = threadIdx.x & 63;
  const float* base = h + lane * 4;
  const int beg = off_dst[d], end = off_dst[d + 1];
  f32x4 acc = {};
  int k = beg + w;
  for (; k + 12 < end; k += 16) {
    int s0 = adj_dst[k], s1 = adj_dst[k + 4], s2 = adj_dst[k + 8], s3 = adj_dst[k + 12];
    if ((unsigned)(s0 - lo) < 4096u) acc += *(const f32x4*)(base + (size_t)s0 * REPH);
    if ((unsigned)(s1 - lo) < 4096u) acc += *(const f32x4*)(base + (size_t)s1 * REPH);
    if ((unsigned)(s2 - lo) < 4096u) acc += *(const f32x4*)(base + (size_t)s2 * REPH);
    if ((unsigned)(s3 - lo) < 4096u) acc += *(const f32x4*)(base + (size_t)s3 * REPH);
  }
  for (; k < end; k += 4) {
    int s = adj_dst[k];
    if ((unsigned)(s - lo) < 4096u) acc += *(const f32x4*)(base + (size_t)s * REPH);
  }
  if (w) part[w - 1][lane] = acc;
  __syncthreads();
  if (w == 0) {
    acc += part[0][lane] + part[1][lane] + part[2][lane];
    size_t o = (size_t)d * REPH + lane * 4;
    if (!first) acc += *(const f32x4*)(Pf + o);
    if (!last) {
      *(f32x4*)(Pf + o) = acc;
    } else {
      f32x4 bb = *(const f32x4*)(b + lane * 4);
      f32x4 mm = *(const f32x4*)(mod + o);
      s16x4 vh, vl;
#pragma unroll
      for (int j = 0; j < 4; ++j) {
        float v = fmaxf(acc[j] + bb[j], 0.f) * expf(-GAMMA_ * mm[j]);
        short hh, ll;
        f2hilo(v, hh, ll);
        vh[j] = hh; vl[j] = ll;
      }
      *(s16x4*)(oh + o) = vh;
      *(s16x4*)(ol + o) = vl;
    }
  }
}

// ---------------- phased normalized agg; C=256; slice 4096 rows ----------------
__global__ __launch_bounds__(256) void aggn256_ph(const float* __restrict__ h,
    const float* __restrict__ b, const float* __restrict__ dinv,
    const float* __restrict__ mod, const int* __restrict__ off_dst,
    const int* __restrict__ adj_dst, float* __restrict__ Pf,
    short* __restrict__ oh, short* __restrict__ ol, int lo, int first, int last) {
  __shared__ f32x4 part[3][64];
  const int d = blockIdx.x, w = threadIdx.x >> 6, lane = threadIdx.x & 63;
  const float* base = h + lane * 4;
  const int beg = off_dst[d], end = off_dst[d + 1];
  f32x4 acc = {};
  int k = beg + w;
  for (; k + 12 < end; k += 16) {
    int s0 = adj_dst[k], s1 = adj_dst[k + 4], s2 = adj_dst[k + 8], s3 = adj_dst[k + 12];
    if ((unsigned)(s0 - lo) < 4096u) acc += *(const f32x4*)(base + (size_t)s0 * REPH) * dinv[s0];
    if ((unsigned)(s1 - lo) < 4096u) acc += *(const f32x4*)(base + (size_t)s1 * REPH) * dinv[s1];
    if ((unsigned)(s2 - lo) < 4096u) acc += *(const f32x4*)(base + (size_t)s2 * REPH) * dinv[s2];
    if ((unsigned)(s3 - lo) < 4096u) acc += *(const f32x4*)(base + (size_t)s3 * REPH) * dinv[s3];
  }
  for (; k < end; k += 4) {
    int s = adj_dst[k];
    if ((unsigned)(s - lo) < 4096u) acc += *(const f32x4*)(base + (size_t)s * REPH) * dinv[s];
  }
  if (w) part[w - 1][lane] = acc;
  __syncthreads();
  if (w == 0) {
    acc += part[0][lane] + part[1][lane] + part[2][lane];
    size_t o = (size_t)d * REPH + lane * 4;
    if (!first) acc += *(const f32x4*)(Pf + o);
    if (!last) {
      *(f32x4*)(Pf + o) = acc;
    } else {
      const float dd = dinv[d];
      f32x4 bb = *(const f32x4*)(b + lane * 4);
      f32x4 self = *(const f32x4*)(h + o);
      f32x4 mm = *(const f32x4*)(mod + o);
      s16x4 vh, vl;
#pragma unroll
      for (int j = 0; j < 4; ++j) {
        float v = fmaxf(acc[j] * dd + self[j] * dd * dd + bb[j], 0.f) * expf(-GAMMA_ * mm[j]);
        short hh, ll;
        f2hilo(v, hh, ll);
        vh[j] = hh; vl[j] = ll;
      }
      *(s16x4*)(oh + o) = vh;
      *(s16x4*)(ol + o) = vl;
    }
  }
}

// ---------------- normalized agg, C=128, single-phase (table 4 MB L2-fits) ----------
__global__ __launch_bounds__(256) void aggn128_v2(const float* __restrict__ h,
    const float* __restrict__ b, const float* __restrict__ dinv,
    const int* __restrict__ off_dst, const int* __restrict__ adj_dst,
    short* __restrict__ oh, short* __restrict__ ol) {
  __shared__ f32x2 part[3][64];
  const int d = blockIdx.x, w = threadIdx.x >> 6, lane = threadIdx.x & 63;
  const float* base = h + lane * 2;
  const int beg = off_dst[d], end = off_dst[d + 1];
  f32x2 acc = {};
  int k = beg + w;
  for (; k + 12 < end; k += 16) {
    int s0 = adj_dst[k], s1 = adj_dst[k + 4], s2 = adj_dst[k + 8], s3 = adj_dst[k + 12];
    float d0 = dinv[s0], d1 = dinv[s1], d2 = dinv[s2], d3 = dinv[s3];
    f32x2 h0 = *(const f32x2*)(base + (size_t)s0 * EMBD);
    f32x2 h1 = *(const f32x2*)(base + (size_t)s1 * EMBD);
    f32x2 h2 = *(const f32x2*)(base + (size_t)s2 * EMBD);
    f32x2 h3 = *(const f32x2*)(base + (size_t)s3 * EMBD);
    acc += h0 * d0 + h1 * d1 + h2 * d2 + h3 * d3;
  }
  for (; k < end; k += 4) {
    int s = adj_dst[k];
    acc += *(const f32x2*)(base + (size_t)s * EMBD) * dinv[s];
  }
  if (w) part[w - 1][lane] = acc;
  __syncthreads();
  if (w == 0) {
    acc += part[0][lane] + part[1][lane] + part[2][lane];
    const float dd = dinv[d];
    size_t o = (size_t)d * EMBD + lane * 2;
    f32x2 bb = *(const f32x2*)(b + lane * 2);
    f32x2 self = *(const f32x2*)(h + o);
    s16x2 vh, vl;
#pragma unroll
    for (int j = 0; j < 2; ++j) {
      float v = fmaxf(acc[j] * dd + self[j] * dd * dd + bb[j], 0.f);
      short hh, ll; f2hilo(v, hh, ll); vh[j] = hh; vl[j] = ll;
    }
    *(s16x2*)(oh + o) = vh;
    *(s16x2*)(ol + o) = vl;
  }
}

// ------- prep: 8 weights (transpose) + x (straight), fp32 -> hi/lo bf16 -------
struct WDesc { const float* src; short* h; short* l; int K; int N; int tr; };
struct WTab { WDesc d[9]; };

__global__ void prep_w(WTab tab) {
  WDesc d = tab.d[blockIdx.y];
  int total = d.K * d.N;
  for (int i = blockIdx.x * 256 + threadIdx.x; i < total; i += 128 * 256) {
    float x;
    if (d.tr) {
      int n = i / d.K, k = i - n * d.K;
      x = d.src[(size_t)k * d.N + n];
    } else {
      x = d.src[i];
    }
    short hh, ll;
    f2hilo(x, hh, ll);
    d.h[i] = hh;
    d.l[i] = ll;
  }
}

// ---------------- split-bf16 MFMA GEMM, pre-split A and W planes ----------------
template<int CB>
__global__ __launch_bounds__(256) void gemmS(const short* __restrict__ Ah,
    const short* __restrict__ Al, const short* __restrict__ Wh,
    const short* __restrict__ Wl, const float* __restrict__ bias, int doRelu,
    float* __restrict__ outF, short* __restrict__ outH, short* __restrict__ outL,
    int K, int Nc) {
  const int w = threadIdx.x >> 6, l = threadIdx.x & 63;
  const int lr = l & 15, lk = l >> 4;
  const int m0 = blockIdx.y * 64 + w * 16;
  const int n0 = blockIdx.x * (CB * 16);
  f32x4 acc[CB] = {};
  const int nks = K >> 5;
  for (int ks = 0; ks < nks; ++ks) {
    const int k0 = (ks << 5) + (lk << 3);
    size_t aoff = (size_t)(m0 + lr) * K + k0;
    bf16x8 ah = *(const bf16x8*)(Ah + aoff);
    bf16x8 al = *(const bf16x8*)(Al + aoff);
#pragma unroll
    for (int cb = 0; cb < CB; ++cb) {
      size_t boff = (size_t)(n0 + (cb << 4) + lr) * K + k0;
      bf16x8 bh = *(const bf16x8*)(Wh + boff);
      bf16x8 bl = *(const bf16x8*)(Wl + boff);
      acc[cb] = __builtin_amdgcn_mfma_f32_16x16x32_bf16(ah, bh, acc[cb], 0, 0, 0);
      acc[cb] = __builtin_amdgcn_mfma_f32_16x16x32_bf16(al, bh, acc[cb], 0, 0, 0);
      acc[cb] = __builtin_amdgcn_mfma_f32_16x16x32_bf16(ah, bl, acc[cb], 0, 0, 0);
    }
  }
#pragma unroll
  for (int cb = 0; cb < CB; ++cb) {
    int col = n0 + (cb << 4) + lr;
    float bv = bias ? bias[col] : 0.f;
#pragma unroll
    for (int r = 0; r < 4; ++r) {
      int row = m0 + (lk << 2) + r;
      float v = acc[cb][r] + bv;
      if (doRelu) v = fmaxf(v, 0.f);
      size_t off = (size_t)row * Nc + col;
      if (outF) outF[off] = v;
      if (outH) {
        short hh, ll;
        f2hilo(v, hh, ll);
        outH[off] = hh;
        outL[off] = ll;
      }
    }
  }
}

// ------- A_hat = H @ H^T: symmetric tiles, LDS-staged float4 stores both ways -------
__global__ __launch_bounds__(256) void ahat_sym(const short* __restrict__ Hh,
    const short* __restrict__ Hl, float* __restrict__ C) {
  __shared__ float sm[128][132];
  int z = blockIdx.x;
  int b = (int)((sqrtf(8.f * (float)z + 1.f) - 1.f) * 0.5f);
  while ((b + 1) * (b + 2) / 2 <= z) ++b;
  while (b * (b + 1) / 2 > z) --b;
  int a = z - b * (b + 1) / 2;  // a <= b
  const int bi = a * 128, bj = b * 128;
  const bool mirror = (a != b);
  const int w = threadIdx.x >> 6, l = threadIdx.x & 63;
  const int lr = l & 15, lk = l >> 4;
  const int ri = w * 32;
  f32x4 acc[2][8] = {};
#pragma unroll
  for (int ks = 0; ks < 4; ++ks) {
    const int k0 = (ks << 5) + (lk << 3);
    bf16x8 ah[2], al[2];
#pragma unroll
    for (int rb = 0; rb < 2; ++rb) {
      size_t off = (size_t)(bi + ri + (rb << 4) + lr) * EMBD + k0;
      ah[rb] = *(const bf16x8*)(Hh + off);
      al[rb] = *(const bf16x8*)(Hl + off);
    }
#pragma unroll
    for (int cb = 0; cb < 8; ++cb) {
      size_t off = (size_t)(bj + (cb << 4) + lr) * EMBD + k0;
      bf16x8 bh = *(const bf16x8*)(Hh + off);
      bf16x8 bl = *(const bf16x8*)(Hl + off);
#pragma unroll
      for (int rb = 0; rb < 2; ++rb) {
        acc[rb][cb] = __builtin_amdgcn_mfma_f32_16x16x32_bf16(ah[rb], bh, acc[rb][cb], 0, 0, 0);
        acc[rb][cb] = __builtin_amdgcn_mfma_f32_16x16x32_bf16(al[rb], bh, acc[rb][cb], 0, 0, 0);
        acc[rb][cb] = __builtin_amdgcn_mfma_f32_16x16x32_bf16(ah[rb], bl, acc[rb][cb], 0, 0, 0);
      }
    }
  }
#pragma unroll
  for (int rb = 0; rb < 2; ++rb)
#pragma unroll
    for (int cb = 0; cb < 8; ++cb) {
      int r0 = ri + (rb << 4) + (lk << 2);
      int c0 = (cb << 4) + lr;
#pragma unroll
      for (int r = 0; r < 4; ++r) sm[r0 + r][c0] = acc[rb][cb][r];
    }
  __syncthreads();
  for (int idx = threadIdx.x; idx < 128 * 32; idx += 256) {
    int row = idx >> 5, c4 = (idx & 31) << 2;
    float4 v = *(const float4*)&sm[row][c4];
    *(float4*)&C[(size_t)(bi + row) * NN + bj + c4] = v;
  }
  if (mirror) {
    for (int idx = threadIdx.x; idx < 128 * 32; idx += 256) {
      int row = idx >> 5, c4 = (idx & 31) << 2;
      float4 v;
      v.x = sm[c4 + 0][row]; v.y = sm[c4 + 1][row];
      v.z = sm[c4 + 2][row]; v.w = sm[c4 + 3][row];
      *(float4*)&C[(size_t)(bj + row) * NN + bi + c4] = v;
    }
  }
}

// ---------------- launch ----------------

extern "C" void kernel_launch(void* const* d_in, const int* in_sizes, int n_in,
                              void* d_out, int out_size, void* d_ws, size_t ws_size,
                              hipStream_t stream) {
  const float* x      = (const float*)d_in[0];
  const int*   ei     = (const int*)d_in[1];
  const float* res_W1 = (const float*)d_in[2];
  const float* res_b1 = (const float*)d_in[3];
  const float* res_W2 = (const float*)d_in[4];
  const float* res_b2 = (const float*)d_in[5];
  const float* fc_W1  = (const float*)d_in[6];
  const float* fc_b1  = (const float*)d_in[7];
  const float* fc_W2  = (const float*)d_in[8];
  const float* fc_b2  = (const float*)d_in[9];
  const float* g_W0   = (const float*)d_in[10];
  const float* g_b0   = (const float*)d_in[11];
  const float* g_W1   = (const float*)d_in[12];
  const float* g_b1   = (const float*)d_in[13];
  const float* g_W2   = (const float*)d_in[14];
  const float* g_b2   = (const float*)d_in[15];
  const float* dec_W1 = (const float*)d_in[16];
  const float* dec_b1 = (const float*)d_in[17];
  const float* dec_W2 = (const float*)d_in[18];
  const float* dec_b2 = (const float*)d_in[19];

  float* out   = (float*)d_out;
  float* X_hat = out;
  float* A_hat = out + (size_t)NN * FF;
  float* R     = A_hat + (size_t)NN * NN;

  char* ws = (char*)d_ws;
  size_t o = 0;
  auto alloc = [&](size_t bytes) -> void* {
    void* p = ws + o;
    o += (bytes + 1023) & ~(size_t)1023;
    return p;
  };
  const size_t MB = 1024 * 1024;
  // fixed (~4.3 MB)
  int* cnt_src = (int*)alloc(NN * 4);
  int* cnt_dst = (int*)alloc(NN * 4);
  int* cur_src = (int*)alloc(NN * 4);
  int* cur_dst = (int*)alloc(NN * 4);
  int* off_src = (int*)alloc((NN + 1) * 4);
  int* off_dst = (int*)alloc((NN + 1) * 4);
  int* adj_src = (int*)alloc((size_t)EE * 4);
  int* adj_dst = (int*)alloc((size_t)EE * 4);
  float* dinv  = (float*)alloc(NN * 4);
  short* Wt_h  = (short*)alloc(524288 * 2);
  short* Wt_l  = (short*)alloc(524288 * 2);
  // large buffers (aliases verified by stage lifetimes, ~96 MB total)
  char* bS1f = (char*)alloc(16 * MB);  // S1f -> G1f
  char* bS1h = (char*)alloc(8 * MB);   // S1h -> D1h
  char* bS1l = (char*)alloc(8 * MB);   // S1l -> D1l
  char* bX   = (char*)alloc(8 * MB);   // Xh+Xl -> B4f
  char* bR   = (char*)alloc(8 * MB);   // Rh+Rl -> M2h+M2l
  char* bB3f = (char*)alloc(8 * MB);   // B3f
  char* bB3  = (char*)alloc(8 * MB);   // B3h+B3l
  char* bB1f = (char*)alloc(8 * MB);   // B1f
  char* bPf  = (char*)alloc(8 * MB);   // Pf phase-partials
  char* bM1  = (char*)alloc(8 * MB);   // M1h+M1l
  char* bG2f = (char*)alloc(4 * MB);   // G2f
  char* bH   = (char*)alloc(4 * MB);   // Hh+Hl

  float* S1f = (float*)bS1f;           float* G1f = (float*)bS1f;
  short* S1h = (short*)bS1h;           short* D1h = (short*)bS1h;
  short* S1l = (short*)bS1l;           short* D1l = (short*)bS1l;
  short* Xh  = (short*)bX;             short* Xl  = (short*)(bX + 4 * MB);
  float* B4f = (float*)bX;
  short* Rh  = (short*)bR;             short* Rl  = (short*)(bR + 4 * MB);
  short* M2h = (short*)bR;             short* M2l = (short*)(bR + 4 * MB);
  float* B3f = (float*)bB3f;
  short* B3h = (short*)bB3;            short* B3l = (short*)(bB3 + 4 * MB);
  float* B1f = (float*)bB1f;
  float* Pf  = (float*)bPf;
  short* M1h = (short*)bM1;            short* M1l = (short*)(bM1 + 4 * MB);
  float* G2f = (float*)bG2f;
  short* Hh  = (short*)bH;             short* Hl  = (short*)(bH + 2 * MB);

  // Wt offsets (elements), stored [N][K]
  const int o_resW2 = 0;
  const int o_fcW1  = 131072;
  const int o_fcW2  = 196608;
  const int o_gW0   = 262144;
  const int o_gW1   = 327680;
  const int o_gW2   = 393216;
  const int o_decW1 = 425984;
  const int o_decW2 = 458752;

  hipMemsetAsync(cnt_src, 0, (size_t)NN * 4 * 4, stream);

  count_kernel<<<EE / 256, 256, 0, stream>>>(ei, cnt_src, cnt_dst);
  scan_kernel<<<2, 1024, 0, stream>>>(cnt_src, cnt_dst, off_src, off_dst, dinv);
  fill_kernel<<<EE / 256, 256, 0, stream>>>(ei, off_src, off_dst, cur_src, cur_dst,
                                            adj_src, adj_dst);

  WTab tab;
  tab.d[0] = {res_W2, Wt_h + o_resW2, Wt_l + o_resW2, RESH, FF,   1};
  tab.d[1] = {fc_W1,  Wt_h + o_fcW1,  Wt_l + o_fcW1,  FF,   REPH, 1};
  tab.d[2] = {fc_W2,  Wt_h + o_fcW2,  Wt_l + o_fcW2,  REPH, REPH, 1};
  tab.d[3] = {g_W0,   Wt_h + o_gW0,   Wt_l + o_gW0,   FF,   REPH, 1};
  tab.d[4] = {g_W1,   Wt_h + o_gW1,   Wt_l + o_gW1,   REPH, REPH, 1};
  tab.d[5] = {g_W2,   Wt_h + o_gW2,   Wt_l + o_gW2,   REPH, EMBD, 1};
  tab.d[6] = {dec_W1, Wt_h + o_decW1, Wt_l + o_decW1, EMBD, REPH, 1};
  tab.d[7] = {dec_W2, Wt_h + o_decW2, Wt_l + o_decW2, REPH, FF,   1};
  tab.d[8] = {x,      Xh,             Xl,             FF,   NN,   0};
  prep_w<<<dim3(128, 9), 256, 0, stream>>>(tab);

  // S1 = split(relu(A @ res_W1 + res_b1)) — 4 phases of 2048 table rows
  s1_ph<<<NN, 256, 0, stream>>>(res_W1, res_b1, off_src, adj_src, S1f, S1h, S1l, 0,    1, 0);
  s1_ph<<<NN, 256, 0, stream>>>(res_W1, res_b1, off_src, adj_src, S1f, S1h, S1l, 2048, 0, 0);
  s1_ph<<<NN, 256, 0, stream>>>(res_W1, res_b1, off_src, adj_src, S1f, S1h, S1l, 4096, 0, 0);
  s1_ph<<<NN, 256, 0, stream>>>(res_W1, res_b1, off_src, adj_src, S1f, S1h, S1l, 6144, 0, 1);
  // R = relu(S1 @ res_W2 + res_b2)
  gemmS<4><<<dim3(4, 128), 256, 0, stream>>>(S1h, S1l, Wt_h + o_resW2, Wt_l + o_resW2,
      res_b2, 1, R, Rh, Rl, RESH, FF);
  // B3 = relu(R @ fc_W1 + fc_b1)
  gemmS<4><<<dim3(4, 128), 256, 0, stream>>>(Rh, Rl, Wt_h + o_fcW1, Wt_l + o_fcW1,
      fc_b1, 1, B3f, B3h, B3l, FF, REPH);
  // B1 = x @ g_W0
  gemmS<4><<<dim3(4, 128), 256, 0, stream>>>(Xh, Xl, Wt_h + o_gW0, Wt_l + o_gW0,
      nullptr, 0, B1f, nullptr, nullptr, FF, REPH);
  // M1 = split(relu(agg0(B1)+g_b0)*exp(-g*B3)) — 2 phases
  agg0_ph<<<NN, 256, 0, stream>>>(B1f, g_b0, B3f, off_dst, adj_dst, Pf, M1h, M1l, 0,    1, 0);
  agg0_ph<<<NN, 256, 0, stream>>>(B1f, g_b0, B3f, off_dst, adj_dst, Pf, M1h, M1l, 4096, 0, 1);
  // G1 = M1 @ g_W1
  gemmS<4><<<dim3(4, 128), 256, 0, stream>>>(M1h, M1l, Wt_h + o_gW1, Wt_l + o_gW1,
      nullptr, 0, G1f, nullptr, nullptr, REPH, REPH);
  // B4 = relu(B3 @ fc_W2 + fc_b2)
  gemmS<4><<<dim3(4, 128), 256, 0, stream>>>(B3h, B3l, Wt_h + o_fcW2, Wt_l + o_fcW2,
      fc_b2, 1, B4f, nullptr, nullptr, REPH, REPH);
  // M2 = split(relu(aggn(G1)+g_b1)*exp(-g*B4)) — 2 phases
  aggn256_ph<<<NN, 256, 0, stream>>>(G1f, g_b1, dinv, B4f, off_dst, adj_dst, Pf,
                                     M2h, M2l, 0,    1, 0);
  aggn256_ph<<<NN, 256, 0, stream>>>(G1f, g_b1, dinv, B4f, off_dst, adj_dst, Pf,
                                     M2h, M2l, 4096, 0, 1);
  // G2 = M2 @ g_W2  [N, EMBD]
  gemmS<2><<<dim3(4, 128), 256, 0, stream>>>(M2h, M2l, Wt_h + o_gW2, Wt_l + o_gW2,
      nullptr, 0, G2f, nullptr, nullptr, REPH, EMBD);
  // H = split(relu(aggn(G2)+g_b2))
  aggn128_v2<<<NN, 256, 0, stream>>>(G2f, g_b2, dinv, off_dst, adj_dst, Hh, Hl);
  // D1 = relu(H @ dec_W1 + dec_b1)
  gemmS<4><<<dim3(4, 128), 256, 0, stream>>>(Hh, Hl, Wt_h + o_decW1, Wt_l + o_decW1,
      dec_b1, 1, nullptr, D1h, D1l, EMBD, REPH);
  // X_hat = relu(D1 @ dec_W2 + dec_b2)
  gemmS<4><<<dim3(4, 128), 256, 0, stream>>>(D1h, D1l, Wt_h + o_decW2, Wt_l + o_decW2,
      dec_b2, 1, X_hat, nullptr, nullptr, REPH, FF);
  // A_hat = H @ H^T (symmetric)
  ahat_sym<<<2080, 256, 0, stream>>>(Hh, Hl, A_hat);
}